// Round 9
// baseline (258.693 us; speedup 1.0000x reference)
//
#include <hip/hip_runtime.h>
#include <hip/hip_bf16.h>

#define NB 4
#define CC 512
#define TT 4096
#define C3 1536
#define CQK 1024
#define NTC (NB*TT*CC)   // 8388608 elems per [N,T,C] tensor

typedef __attribute__((ext_vector_type(4))) float f32x4;
typedef __attribute__((ext_vector_type(8))) short short8;
typedef unsigned short ushort;
typedef __attribute__((ext_vector_type(8))) ushort u16x8;

__device__ __forceinline__ ushort f2bf(float f){
    union { float f; unsigned u; } x; x.f = f;
    unsigned r = x.u + 0x7fffu + ((x.u >> 16) & 1u);   // RNE
    return (ushort)(r >> 16);
}

__device__ __forceinline__ ushort2 pk2bf(float a, float b){
    float2 f2; f2.x = a; f2.y = b;
    __hip_bfloat162 h = __float22bfloat162_rn(f2);     // v_cvt_pk_bf16_f32 (RNE)
    union { __hip_bfloat162 h2; ushort2 u2; } u; u.h2 = h;
    return u.u2;
}

__device__ __forceinline__ void gload16(const void* g, void* l){
    __builtin_amdgcn_global_load_lds((const __attribute__((address_space(1))) void*)g,
                                     (__attribute__((address_space(3))) void*)l,
                                     16, 0, 0);
}

// ---------------- K0: weight fp32 -> bf16 ----------------
__global__ __launch_bounds__(256) void wcvt(const float* __restrict__ Wi,
                                            const float* __restrict__ Wo,
                                            ushort* __restrict__ Wb,
                                            ushort* __restrict__ Wob){
    int idx0 = blockIdx.x * 1024 + threadIdx.x;
    for (int i = 0; i < 4; ++i){
        int idx = idx0 + i*256;
        const float* src; ushort* dst; int j;
        if (idx < 196608){ src = Wi; dst = Wb;  j = idx; }
        else             { src = Wo; dst = Wob; j = idx - 196608; }
        f32x4 vv = *((const f32x4*)src + j);
        ushort4 o;
        *(ushort2*)&o.x = pk2bf(vv[0], vv[1]);
        *(ushort2*)&o.z = pk2bf(vv[2], vv[3]);
        *((ushort4*)dst + j) = o;
    }
}

// ---------------- K1: fused transpose+cvt + QKV projection GEMM ----------------
// Tile: m=256 (t-dim, 1KB fp32 bursts), co=128, kb=32ci x 16 iters.
// Araw (fp32, async) -> register cvt -> sA (padded 80B rows); B double-buffered async.
__global__ __launch_bounds__(256, 2) void proj_gemm(const float* __restrict__ q,
                                                    const float* __restrict__ k,
                                                    const float* __restrict__ v,
                                                    const ushort* __restrict__ Wb,
                                                    const float* __restrict__ b_in,
                                                    ushort* __restrict__ P,
                                                    ushort* __restrict__ Vt){
    __shared__ __align__(16) ushort smem[34816];   // 69632 B
    ushort* sA   = smem;                       // 256 rows x 40 ushorts = 20480
    ushort* sB0  = smem + 10240;               // 128 x 32 = 4096
    ushort* sB1  = smem + 14336;               // 4096
    float*  Araw = (float*)(smem + 18432);     // 32 rows x 256 floats = 32 KB
    const int tid = threadIdx.x;
    const int bid = blockIdx.x;
    const int mtile  = ((bid & 7) << 3) | ((bid >> 3) & 7);   // 0..63
    const int cotile = bid >> 6;                               // 0..11
    const int co0 = cotile * 128;
    const int m0  = mtile * 256;
    const int which = co0 >> 9;                // 0:q 1:k 2:v
    const float* src = (which == 0) ? q : (which == 1) ? k : v;
    const int n  = m0 >> 12, t0 = m0 & 4095;
    const ushort* Bbase = Wb + (size_t)co0*CC;
    const int w = tid >> 6, lane = tid & 63;
    const int l15 = lane & 15, quad = lane >> 4;

    // A staging: wave w loads ci-rows [w*8, w*8+8), each row 1 KB (64 lanes x 16B)
    const float* Agbase = src + (size_t)n*CC*TT + (size_t)(w*8)*TT + t0 + lane*4;
    float* lAr = Araw + w*8*256 + lane*4;      // wave-uniform base + lane*16B

    // B staging: slot=(co,k4), value chunk kk = k4^(co&3) at position k4
    const ushort* gB[2]; int lBoff[2];
    for (int i = 0; i < 2; ++i){
        int slot = i*256 + tid;
        int co = slot >> 2, k4 = slot & 3, kk = k4 ^ (co & 3);
        gB[i] = Bbase + (size_t)co*CC + kk*8;
        lBoff[i] = (i*256 + (tid & ~63)) * 8;
    }

    // prologue: kb=0
    for (int r = 0; r < 8; ++r)
        gload16(Agbase + (size_t)r*TT, lAr + r*256);
    for (int i = 0; i < 2; ++i)
        gload16(gB[i], sB0 + lBoff[i]);

    f32x4 acc[4][8] = {};
    for (int kb = 0; kb < 16; ++kb){
        ushort* sBc = (kb & 1) ? sB1 : sB0;
        ushort* sBn = (kb & 1) ? sB0 : sB1;
        __syncthreads();       // asyncs for kb landed; prior MFMA/LDS reads done
        // transpose Araw (fp32, own wave's 8 ci-rows) -> sA (bf16, slot w)
        f32x4 cur[8];
        #pragma unroll
        for (int j = 0; j < 8; ++j)
            cur[j] = *(const f32x4*)(Araw + (w*8 + j)*256 + lane*4);
        #pragma unroll
        for (int tj = 0; tj < 4; ++tj){
            int m = lane*4 + tj;
            int pos = (w + lane + tj) & 3;
            u16x8 o;
            #pragma unroll
            for (int j = 0; j < 8; j += 2){
                ushort2 p = pk2bf(cur[j][tj], cur[j+1][tj]);
                o[j] = p.x; o[j+1] = p.y;
            }
            *(u16x8*)&sA[m*40 + pos*8] = o;
        }
        __syncthreads();       // sA visible; Araw consumed
        if (kb < 15){          // issue kb+1 asyncs; covered by MFMA below
            const float* Agn = Agbase + (size_t)((kb+1)*32)*TT;
            for (int r = 0; r < 8; ++r)
                gload16(Agn + (size_t)r*TT, lAr + r*256);
            for (int i = 0; i < 2; ++i)
                gload16(gB[i] + (kb+1)*32, sBn + lBoff[i]);
        }
        short8 aF[4], bF[8];
        for (int mi = 0; mi < 4; ++mi){
            int m = w*64 + mi*16 + l15;
            aF[mi] = *(const short8*)&sA[m*40 + ((quad + (m>>2) + (m&3)) & 3)*8];
        }
        for (int ni = 0; ni < 8; ++ni){
            int co = ni*16 + l15;
            bF[ni] = *(const short8*)&sBc[co*32 + (quad ^ (co & 3))*8];
        }
        for (int mi = 0; mi < 4; ++mi)
            for (int ni = 0; ni < 8; ++ni)
                acc[mi][ni] = __builtin_amdgcn_mfma_f32_16x16x32_bf16(
                    aF[mi], bF[ni], acc[mi][ni], 0, 0, 0);
    }

    float bj[8];
    for (int ni = 0; ni < 8; ++ni) bj[ni] = b_in[co0 + ni*16 + l15];

    __syncthreads();                 // staging done; reuse LDS as sOut
    ushort* sOut = smem;
    if (which < 2){
        // sOut[m (256)][136]
        for (int mi = 0; mi < 4; ++mi){
            int mrow = w*64 + mi*16 + quad*4;
            for (int ni = 0; ni < 8; ++ni){
                int col = ni*16 + l15;
                for (int r = 0; r < 4; ++r)
                    sOut[(mrow + r)*136 + col] = f2bf(acc[mi][ni][r] + bj[ni]);
            }
        }
    } else {
        // sOut[co (128)][264]  (transposed for Vt)
        for (int mi = 0; mi < 4; ++mi){
            int mrow = w*64 + mi*16 + quad*4;
            for (int ni = 0; ni < 8; ++ni){
                int col = ni*16 + l15;
                ushort4 o4;
                o4.x = f2bf(acc[mi][ni][0] + bj[ni]);
                o4.y = f2bf(acc[mi][ni][1] + bj[ni]);
                o4.z = f2bf(acc[mi][ni][2] + bj[ni]);
                o4.w = f2bf(acc[mi][ni][3] + bj[ni]);
                *(ushort4*)&sOut[col*264 + mrow] = o4;
            }
        }
    }
    __syncthreads();
    if (which < 2){
        for (int i = 0; i < 16; ++i){
            int flat = i*256 + tid;
            int row = flat >> 4, cs = (flat & 15)*8;
            u16x8 val = *(const u16x8*)&sOut[row*136 + cs];
            *(u16x8*)(P + (size_t)(m0 + row)*CQK + which*512 + (co0 & 511) + cs) = val;
        }
    } else {
        for (int i = 0; i < 16; ++i){
            int flat = i*256 + tid;
            int row = flat >> 5, cs = (flat & 31)*8;    // row = local co (d), cs along t
            int cl = (co0 - 1024) + row;
            int h = cl >> 6, d = cl & 63;
            u16x8 val = *(const u16x8*)&sOut[row*264 + cs];
            *(u16x8*)(Vt + (((size_t)n*8 + h)*64 + d)*TT + t0 + cs) = val;
        }
    }
}

// ---------------- K2: attention, one block per (n,chunk), 8 heads pipelined ----------------
__global__ __launch_bounds__(256) void attn_kernel(const ushort* __restrict__ P,
                                                   const ushort* __restrict__ Vt,
                                                   const float* __restrict__ masks,
                                                   ushort* __restrict__ ctx){
    __shared__ __align__(16) ushort sQ[2][4096], sK[2][4096], sV[2][4096];
    __shared__ __align__(16) ushort sP[64*72];   // P-matrix, then reused as O tile
    const int bid = blockIdx.x;
    const int n = bid >> 6, ch = bid & 63;
    const int tid = threadIdx.x, lane = tid & 63, w = tid >> 6;
    const int l15 = lane & 15, quad = lane >> 4;
    const size_t rowbase = (size_t)n*TT + (size_t)ch*64;
    const int m0w = w*16;

    // per-slot load descriptors (shared by all heads)
    int rr[2], kk8[2], lbase[2];
    for (int i = 0; i < 2; ++i){
        int slot = i*256 + tid;
        rr[i] = slot >> 3;
        kk8[i] = (slot & 7) ^ (rr[i] & 7);
        lbase[i] = (i*256 + (tid & ~63)) * 8;
    }
    auto issue = [&](int hh, int buf){
        for (int i = 0; i < 2; ++i){
            const ushort* gq = P + (rowbase + rr[i])*CQK + hh*64 + kk8[i]*8;
            gload16(gq,       &sQ[buf][lbase[i]]);
            gload16(gq + 512, &sK[buf][lbase[i]]);
            const ushort* gv = Vt + (((size_t)n*8 + hh)*64 + rr[i])*TT + ch*64 + kk8[i]*8;
            gload16(gv,       &sV[buf][lbase[i]]);
        }
    };

    // mask add (head-independent)
    float madd[4];
    for (int ni = 0; ni < 4; ++ni){
        float mv = masks[(size_t)n*TT + ch*64 + ni*16 + l15];
        madd[ni] = (mv > 0.f) ? 0.f : -1e9f;
    }

    issue(0, 0);
    for (int h = 0; h < 8; ++h){
        const int cb = h & 1;
        __syncthreads();              // loads for h landed; sP safe to rewrite
        if (h < 7) issue(h+1, cb^1);  // covered by this head's compute
        // S = Q K^T
        short8 aQ[2]; f32x4 accS[4] = {};
        for (int ks = 0; ks < 2; ++ks){
            int m = m0w + l15;
            aQ[ks] = *(const short8*)&sQ[cb][(m*8 + ((ks*4 + quad) ^ (m & 7)))*8];
        }
        for (int ni = 0; ni < 4; ++ni)
            for (int ks = 0; ks < 2; ++ks){
                int m = ni*16 + l15;
                short8 bK = *(const short8*)&sK[cb][(m*8 + ((ks*4 + quad) ^ (m & 7)))*8];
                accS[ni] = __builtin_amdgcn_mfma_f32_16x16x32_bf16(aQ[ks], bK, accS[ni], 0,0,0);
            }
        // softmax over 64 key cols
        float s[4][4];
        for (int ni = 0; ni < 4; ++ni)
            for (int r = 0; r < 4; ++r) s[ni][r] = accS[ni][r]*0.125f + madd[ni];
        float ex[4][4];
        for (int r = 0; r < 4; ++r){
            float m1 = fmaxf(fmaxf(s[0][r], s[1][r]), fmaxf(s[2][r], s[3][r]));
            for (int d = 1; d < 16; d <<= 1) m1 = fmaxf(m1, __shfl_xor(m1, d));
            float a = 0.f;
            for (int ni = 0; ni < 4; ++ni){ float e = __expf(s[ni][r] - m1); ex[ni][r] = e; a += e; }
            for (int d = 1; d < 16; d <<= 1) a += __shfl_xor(a, d);
            float rs = 1.0f / a;
            for (int ni = 0; ni < 4; ++ni)
                sP[(m0w + quad*4 + r)*72 + ni*16 + l15] = f2bf(ex[ni][r] * rs);
        }
        // O = P V   (sP rows wave-private)
        short8 aP[2]; f32x4 accO[4] = {};
        for (int ks = 0; ks < 2; ++ks)
            aP[ks] = *(const short8*)&sP[(m0w + l15)*72 + ks*32 + quad*8];
        for (int ni = 0; ni < 4; ++ni)
            for (int ks = 0; ks < 2; ++ks){
                int m = ni*16 + l15;
                short8 bV = *(const short8*)&sV[cb][(m*8 + ((ks*4 + quad) ^ (m & 7)))*8];
                accO[ni] = __builtin_amdgcn_mfma_f32_16x16x32_bf16(aP[ks], bV, accO[ni], 0,0,0);
            }
        // O -> sP (reuse, own rows), then vectorized 128B-row stores
        for (int ni = 0; ni < 4; ++ni)
            for (int r = 0; r < 4; ++r)
                sP[(m0w + quad*4 + r)*72 + ni*16 + l15] = f2bf(accO[ni][r]);
        __syncthreads();
        for (int i = 0; i < 2; ++i){
            int flat = i*256 + tid;
            int row = flat >> 3, cs = (flat & 7)*8;
            u16x8 val = *(const u16x8*)&sP[row*72 + cs];
            *(u16x8*)(ctx + (rowbase + row)*CC + h*64 + cs) = val;
        }
    }
}

// ---------------- K3: out-projection, 128m x 64co tiles, LDS epilogue ----------------
__global__ __launch_bounds__(256) void out_gemm(const ushort* __restrict__ ctx,
                                                const ushort* __restrict__ Wob,
                                                const float* __restrict__ b_out,
                                                const float* __restrict__ x,
                                                const float* __restrict__ masks,
                                                float* __restrict__ out){
    __shared__ __align__(16) ushort smem[16896];   // staging 16K+8K, then f32 out tile
    ushort* sA = smem;            // 128*64
    ushort* sB = smem + 128*64;   // 64*64
    float* fOut = (float*)smem;   // [64 co][132] f32
    const int tid = threadIdx.x;
    const int bid = blockIdx.x;
    const int mtile  = ((bid & 7) << 4) | ((bid >> 3) & 15);
    const int cotile = bid >> 7;               // 0..7
    const int co0 = cotile * 64;
    const int m0  = mtile * 128;
    const int n = m0 >> 12, t0 = m0 & 4095;
    const ushort* Abase = ctx + (size_t)m0*CC;
    const ushort* Bbase = Wob + (size_t)co0*CC;
    const int w = tid >> 6, lane = tid & 63;
    const int wr = w >> 1, wc = w & 1;
    const int l15 = lane & 15, quad = lane >> 4;

    const ushort* gA[4]; ushort* lA[4];
    const ushort* gB[2]; ushort* lB[2];
    for (int i = 0; i < 4; ++i){
        int slot = i*256 + tid;
        int m = slot >> 3, k8 = slot & 7, kk = k8 ^ (m & 7);
        gA[i] = Abase + (size_t)m*CC + kk*8;
        lA[i] = sA + (i*256 + (tid & ~63)) * 8;
    }
    for (int i = 0; i < 2; ++i){
        int slot = i*256 + tid;
        int m = slot >> 3, k8 = slot & 7, kk = k8 ^ (m & 7);
        gB[i] = Bbase + (size_t)m*CC + kk*8;
        lB[i] = sB + (i*256 + (tid & ~63)) * 8;
    }

    f32x4 acc[4][2] = {};
    for (int kb = 0; kb < 8; ++kb){
        __syncthreads();
        for (int i = 0; i < 4; ++i) gload16(gA[i] + kb*64, lA[i]);
        for (int i = 0; i < 2; ++i) gload16(gB[i] + kb*64, lB[i]);
        __syncthreads();
        for (int ks = 0; ks < 2; ++ks){
            short8 aF[4], bF[2];
            for (int mi = 0; mi < 4; ++mi){
                int m = wr*64 + mi*16 + l15;
                aF[mi] = *(const short8*)&sA[(m*8 + ((ks*4 + quad) ^ (m & 7)))*8];
            }
            for (int ni = 0; ni < 2; ++ni){
                int m = wc*32 + ni*16 + l15;
                bF[ni] = *(const short8*)&sB[(m*8 + ((ks*4 + quad) ^ (m & 7)))*8];
            }
            for (int mi = 0; mi < 4; ++mi)
                for (int ni = 0; ni < 2; ++ni)
                    acc[mi][ni] = __builtin_amdgcn_mfma_f32_16x16x32_bf16(
                        aF[mi], bF[ni], acc[mi][ni], 0, 0, 0);
        }
    }
    float bo[2];
    for (int ni = 0; ni < 2; ++ni) bo[ni] = b_out[co0 + wc*32 + ni*16 + l15];

    __syncthreads();                 // staging done; reuse LDS as fOut[co][t]
    for (int mi = 0; mi < 4; ++mi){
        int tl = wr*64 + mi*16 + quad*4;
        for (int ni = 0; ni < 2; ++ni){
            int cl = wc*32 + ni*16 + l15;
            f32x4 vv;
            for (int r = 0; r < 4; ++r) vv[r] = acc[mi][ni][r] + bo[ni];
            *(f32x4*)&fOut[cl*132 + tl] = vv;
        }
    }
    __syncthreads();
    for (int i = 0; i < 8; ++i){
        int flat = i*256 + tid;
        int co = flat >> 5, ts = (flat & 31)*4;
        f32x4 a = *(const f32x4*)&fOut[co*132 + ts];
        f32x4 mk = *(const f32x4*)(masks + (size_t)n*TT + t0 + ts);
        f32x4 xv = *(const f32x4*)(x + ((size_t)n*CC + co0 + co)*TT + t0 + ts);
        f32x4 o;
        for (int r = 0; r < 4; ++r) o[r] = a[r]*mk[r] + xv[r];
        *(f32x4*)(out + ((size_t)n*CC + co0 + co)*TT + t0 + ts) = o;
    }
}

// ---------------- K4: InstanceNorm over T per (n,c), in place ----------------
__global__ __launch_bounds__(256) void inorm(float* __restrict__ out){
    __shared__ float sS[4], sQ2[4];
    float* row = out + (size_t)blockIdx.x * TT;
    f32x4 vbuf[4];
    float s = 0.f, ss = 0.f;
    for (int i = 0; i < 4; ++i){
        f32x4 vv = *(const f32x4*)(row + (size_t)(i*256 + threadIdx.x)*4);
        vbuf[i] = vv;
        for (int r = 0; r < 4; ++r){ s += vv[r]; ss += vv[r]*vv[r]; }
    }
    for (int d = 1; d < 64; d <<= 1){ s += __shfl_xor(s, d); ss += __shfl_xor(ss, d); }
    int w = threadIdx.x >> 6;
    if ((threadIdx.x & 63) == 0){ sS[w] = s; sQ2[w] = ss; }
    __syncthreads();
    s  = sS[0] + sS[1] + sS[2] + sS[3];
    ss = sQ2[0] + sQ2[1] + sQ2[2] + sQ2[3];
    float mean = s * (1.0f/TT);
    float var  = ss * (1.0f/TT) - mean*mean;
    float rstd = rsqrtf(var + 1e-5f);
    for (int i = 0; i < 4; ++i){
        f32x4 vv = vbuf[i], o;
        for (int r = 0; r < 4; ++r) o[r] = (vv[r] - mean) * rstd;
        *(f32x4*)(row + (size_t)(i*256 + threadIdx.x)*4) = o;
    }
}

extern "C" void kernel_launch(void* const* d_in, const int* in_sizes, int n_in,
                              void* d_out, int out_size, void* d_ws, size_t ws_size,
                              hipStream_t stream) {
    const float* x     = (const float*)d_in[0];
    const float* q     = (const float*)d_in[1];
    const float* k     = (const float*)d_in[2];
    const float* v     = (const float*)d_in[3];
    const float* masks = (const float*)d_in[4];
    const float* W_in  = (const float*)d_in[5];
    const float* b_in  = (const float*)d_in[6];
    const float* W_out = (const float*)d_in[7];
    const float* b_out = (const float*)d_in[8];
    float* out = (float*)d_out;

    ushort* ws  = (ushort*)d_ws;
    ushort* ctx = ws;                           // NTC bf16 (attention output)
    ushort* Wb  = ws + (size_t)NTC;             // 786432
    ushort* Wob = Wb + 786432;                  // 262144
    ushort* P   = Wob + 262144;                 // NB*TT*CQK (Q,K projected)
    ushort* Vt  = P + (size_t)NB*TT*CQK;        // NTC (V projected, transposed)

    wcvt<<<256, 256, 0, stream>>>(W_in, W_out, Wb, Wob);
    proj_gemm<<<768, 256, 0, stream>>>(q, k, v, Wb, b_in, P, Vt);
    attn_kernel<<<256, 256, 0, stream>>>(P, Vt, masks, ctx);
    out_gemm<<<1024, 256, 0, stream>>>(ctx, Wob, b_out, x, masks, out);
    inorm<<<2048, 256, 0, stream>>>(out);
}